// Round 14
// baseline (24792.664 us; speedup 1.0000x reference)
//
#include <hip/hip_runtime.h>
#include <hip/hip_bf16.h>

#define T_DIM 8192
#define O_DIM 1024
#define H_DIM 2048
#define G_DIM 6144   // 3*H
#define A_DIM 512
#define CHUNK 512    // steps per scan launch
#define NBLK 256     // scan blocks (1 per CU; forced by 112.6 KB LDS)

// ---- workspace layout (float offsets; total ~46.7 MB, proven safe) ----
#define OFF_GXC   0ull          // CHUNK x 3H fp32            (3,145,728 f)
#define OFF_HTAG  3145728ull    // 2 x H u64 {h,tag}          (8,192 f)
#define OFF_S     3153920ull    // 8192 scores fp32
#define OFF_RED   3162112ull    // max, sum (+pad)            (16 f)
#define OFF_CPART 3162128ull    // 64 x 2048 fp32             (131,072 f)
#define OFF_C     3293200ull    // 2048 fp32
#define OFF_HSBF  3295248ull    // T x H bf16                 (8,388,608 f)

__device__ __forceinline__ float bf2f(unsigned short u) {
  return __uint_as_float(((unsigned)u) << 16);
}
__device__ __forceinline__ unsigned packbf(float a, float b) {
  return (unsigned)__bfloat16_as_ushort(__float2bfloat16(a)) |
         ((unsigned)__bfloat16_as_ushort(__float2bfloat16(b)) << 16);
}

// ---------------- Phase 1: gx chunk = obs_chunk @ W_ih^T + b_ih ----------------
#define BM 64
#define BN 64
#define BK 16
__global__ __launch_bounds__(256) void gemm_gx(
    const float* __restrict__ A,   // CHUNK x O
    const float* __restrict__ B,   // 3H x O
    const float* __restrict__ bias,
    float* __restrict__ C) {       // CHUNK x 3H
  __shared__ float As[BM][BK + 1];
  __shared__ float Bs[BN][BK + 1];
  const int bm = blockIdx.x * BM;
  const int bn = blockIdx.y * BN;
  const int tid = threadIdx.x;
  const int tr = tid / 16, tc = tid % 16;
  float acc[4][4] = {};
  for (int k0 = 0; k0 < O_DIM; k0 += BK) {
    for (int i = tid; i < BM * BK; i += 256) {
      int r = i / BK, c = i % BK;
      As[r][c] = A[(size_t)(bm + r) * O_DIM + k0 + c];
    }
    for (int i = tid; i < BN * BK; i += 256) {
      int r = i / BK, c = i % BK;
      Bs[r][c] = B[(size_t)(bn + r) * O_DIM + k0 + c];
    }
    __syncthreads();
#pragma unroll
    for (int kk = 0; kk < BK; ++kk) {
      float a[4], b[4];
#pragma unroll
      for (int i = 0; i < 4; ++i) a[i] = As[tr * 4 + i][kk];
#pragma unroll
      for (int j = 0; j < 4; ++j) b[j] = Bs[tc * 4 + j][kk];
#pragma unroll
      for (int i = 0; i < 4; ++i)
#pragma unroll
        for (int j = 0; j < 4; ++j) acc[i][j] += a[i] * b[j];
    }
    __syncthreads();
  }
#pragma unroll
  for (int i = 0; i < 4; ++i)
#pragma unroll
    for (int j = 0; j < 4; ++j) {
      int r = bm + tr * 4 + i, cc = bn + tc * 4 + j;
      C[(size_t)r * G_DIM + cc] = acc[i][j] + bias[cc];
    }
}

// unpack-and-FMA one packed-bf16 uint4 (8 cols) against two staged float4s
#define DOTQ(Q, ACC)                                                  \
  do {                                                                \
    ACC += __uint_as_float((Q).x << 16)          * ha.x               \
         + __uint_as_float((Q).x & 0xffff0000u)  * ha.y               \
         + __uint_as_float((Q).y << 16)          * ha.z               \
         + __uint_as_float((Q).y & 0xffff0000u)  * ha.w               \
         + __uint_as_float((Q).z << 16)          * hb.x               \
         + __uint_as_float((Q).z & 0xffff0000u)  * hb.y               \
         + __uint_as_float((Q).w << 16)          * hb.z               \
         + __uint_as_float((Q).w & 0xffff0000u)  * hb.w;              \
  } while (0)

// ---------------- Phase 2: persistent GRU scan -------------------------------
// r12 champion exchange/publish/gates VERBATIM; ONE change: weights live in LDS
// as packed bf16 (96 KB), staged once per launch with coalesced fp32 reads in
// r12's exact interleaved uint4 layout -> per-step dot is byte-identical to
// r12 but sources q from ds_read_b128 (stride-16B, conflict-clean) instead of
// the allocator's per-step L2/L3 re-stream (VGPR=88, FETCH 94MB for 4 rounds).
// 8 waves = 2/SIMD latency hiding. LDS 112.6 KB naturally forces 1 block/CU.
__global__ __launch_bounds__(512, 2) void scan_chunk(
    const float* __restrict__ W_hh,        // 3H x H fp32
    const float* __restrict__ b_hh,        // 3H
    const float* __restrict__ gxc,         // CHUNK x 3H
    unsigned long long* __restrict__ htag, // 2 x H {h,tag}
    unsigned short* __restrict__ hsbf16,   // T x H bf16
    int t0, int nsteps) {
  __shared__ unsigned wlds[24][1024];          // 96 KB: 24 rows x 2048 bf16
  __shared__ float hlbuf[2][H_DIM];            // 16 KB h double-buffer
  __shared__ unsigned long long stage[8];      // publish stage
  const int tid = threadIdx.x;
  const int lane = tid & 63;
  const int wv = tid >> 6;                 // wave 0..7
  const int blk = blockIdx.x;
  const int u = blk * 8 + wv;              // owned unit

  // ---- stage this wave's 3 W_hh rows to LDS (bf16, r12-interleaved layout) ----
#pragma unroll
  for (int r = 0; r < 3; ++r) {
    const float4* wr = (const float4*)(W_hh + (size_t)(r * H_DIM + u) * H_DIM);
    uint4* dst = (uint4*)&wlds[wv * 3 + r][0];
#pragma unroll
    for (int J = 0; J < 4; ++J) {
      const float4 lo = wr[lane + 128 * J];        // coalesced fp32 reads
      const float4 hi = wr[lane + 64 + 128 * J];
      dst[lane + 64 * J] = uint4{packbf(lo.x, lo.y), packbf(lo.z, lo.w),
                                 packbf(hi.x, hi.y), packbf(hi.z, hi.w)};
    }
  }

  float b0 = 0.f, b1 = 0.f, b2 = 0.f;
  if (lane == 0) {
    b0 = b_hh[u]; b1 = b_hh[H_DIM + u]; b2 = b_hh[2 * H_DIM + u];
  }
  __syncthreads();   // wlds ready

  const uint4* w0 = (const uint4*)&wlds[wv * 3 + 0][0];
  const uint4* w1 = (const uint4*)&wlds[wv * 3 + 1][0];
  const uint4* w2 = (const uint4*)&wlds[wv * 3 + 2][0];

  for (int tt = 0; tt < nsteps; ++tt) {
    const int t = t0 + tt;
    const unsigned long long* hin = htag + (size_t)(t & 1) * H_DIM;
    unsigned long long* hout = htag + (size_t)((t + 1) & 1) * H_DIM;
    float* hl = hlbuf[t & 1];              // double-buffered stage

    // gx for owner lane (issued early; hides under poll)
    float gx0 = 0.f, gx1 = 0.f, gx2 = 0.f;
    if (lane == 0) {
      const float* g = gxc + (size_t)tt * G_DIM + u;
      gx0 = g[0]; gx1 = g[H_DIM]; gx2 = g[2 * H_DIM];
    }

    // ---- (A) poll-the-data: 4 u64/thread, coalesced ----
    unsigned long long v[4];
    const unsigned tgt = (unsigned)t;
    for (;;) {
      bool ok = true;
#pragma unroll
      for (int j = 0; j < 4; ++j) {
        v[j] = __hip_atomic_load(hin + tid + 512 * j,
                                 __ATOMIC_RELAXED, __HIP_MEMORY_SCOPE_AGENT);
        ok = ok && ((unsigned)v[j] >= tgt);
      }
      if (ok) break;
      __builtin_amdgcn_s_sleep(1);
    }
#pragma unroll
    for (int j = 0; j < 4; ++j)
      hl[tid + 512 * j] = __uint_as_float((unsigned)(v[j] >> 32));
    __syncthreads();   // (B) hl ready

    // ---- (C) 3 dot products off LDS-resident packed-bf16 weights ----
    float a0 = 0.f, a1 = 0.f, a2 = 0.f;
    const float4* h4 = (const float4*)hl;
#pragma unroll
    for (int J = 0; J < 4; ++J) {
      const float4 ha = h4[lane + 128 * J];
      const float4 hb = h4[lane + 64 + 128 * J];
      const uint4 q0 = w0[lane + 64 * J]; DOTQ(q0, a0);
      const uint4 q1 = w1[lane + 64 * J]; DOTQ(q1, a1);
      const uint4 q2 = w2[lane + 64 * J]; DOTQ(q2, a2);
    }
#pragma unroll
    for (int d = 32; d > 0; d >>= 1) {
      a0 += __shfl_xor(a0, d, 64);
      a1 += __shfl_xor(a1, d, 64);
      a2 += __shfl_xor(a2, d, 64);
    }

    // ---- (D) gates on owner lane; stage {h,tag} in LDS ----
    float hnew = 0.f;
    if (lane == 0) {
      const float rr = 1.f / (1.f + expf(-(gx0 + a0 + b0)));
      const float zz = 1.f / (1.f + expf(-(gx1 + a1 + b1)));
      const float nn = tanhf(gx2 + rr * (a2 + b2));
      hnew = (1.f - zz) * nn + zz * hl[u];
      stage[wv] = ((unsigned long long)__float_as_uint(hnew) << 32) |
                  (unsigned long long)(unsigned)(t + 1);
    }
    __syncthreads();   // (E) stage ready

    // ---- (F) single-wave coalesced publish: one 64B line, one instruction ----
    if (tid < 8) {
      __hip_atomic_store(hout + blk * 8 + tid, stage[tid],
                         __ATOMIC_RELAXED, __HIP_MEMORY_SCOPE_AGENT);
    }
    // ---- (G) attention state (off critical path; drains under next poll) ----
    if (lane == 0) {
      hsbf16[(size_t)t * H_DIM + u] =
          (unsigned short)__bfloat16_as_ushort(__float2bfloat16(hnew));
    }
  }
}

// ---------------- Phase 3a: attention scores (bf16 h_mid, h_last from htag) ---
__global__ __launch_bounds__(256) void attn_scores(
    const unsigned short* __restrict__ hs_bf,
    const unsigned long long* __restrict__ hq,  // slot0 of htag: {h,tag=8192}
    float* __restrict__ s, int n) {
  __shared__ float hl[H_DIM];
  const int tid = threadIdx.x;
  for (int i = tid; i < H_DIM; i += 256)
    hl[i] = __uint_as_float((unsigned)(hq[i] >> 32));
  __syncthreads();
  const int wave = tid >> 6, lane = tid & 63;
  const int t = blockIdx.x * 4 + wave;
  if (t >= n) return;
  const uint4* r4 = (const uint4*)(hs_bf + (size_t)t * H_DIM);
  float sum = 0.f;
#pragma unroll
  for (int u = 0; u < 4; ++u) {
    const int idx = lane + 64 * u;
    uint4 v = r4[idx];
    const float* l = hl + idx * 8;
    sum += bf2f((unsigned short)(v.x & 0xffff)) * l[0];
    sum += bf2f((unsigned short)(v.x >> 16))    * l[1];
    sum += bf2f((unsigned short)(v.y & 0xffff)) * l[2];
    sum += bf2f((unsigned short)(v.y >> 16))    * l[3];
    sum += bf2f((unsigned short)(v.z & 0xffff)) * l[4];
    sum += bf2f((unsigned short)(v.z >> 16))    * l[5];
    sum += bf2f((unsigned short)(v.w & 0xffff)) * l[6];
    sum += bf2f((unsigned short)(v.w >> 16))    * l[7];
  }
#pragma unroll
  for (int d = 32; d > 0; d >>= 1) sum += __shfl_xor(sum, d, 64);
  if (lane == 0) s[t] = sum;
}

// ---------------- Phase 3b: softmax stats ----------------
__global__ __launch_bounds__(1024) void softmax_stats(
    const float* __restrict__ s, int n, float* __restrict__ red) {
  __shared__ float buf[1024];
  const int tid = threadIdx.x;
  float m = -3.4e38f;
  for (int i = tid; i < n; i += 1024) m = fmaxf(m, s[i]);
  buf[tid] = m;
  __syncthreads();
  for (int d = 512; d > 0; d >>= 1) {
    if (tid < d) buf[tid] = fmaxf(buf[tid], buf[tid + d]);
    __syncthreads();
  }
  const float mm = buf[0];
  __syncthreads();
  float sum = 0.f;
  for (int i = tid; i < n; i += 1024) sum += expf(s[i] - mm);
  buf[tid] = sum;
  __syncthreads();
  for (int d = 512; d > 0; d >>= 1) {
    if (tid < d) buf[tid] += buf[tid + d];
    __syncthreads();
  }
  if (tid == 0) { red[0] = mm; red[1] = buf[0]; }
}

// ---------------- Phase 3c: weighted sum partials (bf16 h_mid) ----------------
__global__ __launch_bounds__(256) void attn_wsum(
    const unsigned short* __restrict__ hs_bf, const float* __restrict__ s,
    const float* __restrict__ red, float* __restrict__ c_part, int n) {
  const int tid = threadIdx.x;
  const float m = red[0];
  const float inv = 1.f / red[1];
  const int tchunk = (n + 63) / 64;
  const int t0 = blockIdx.x * tchunk;
  const int t1 = min(t0 + tchunk, n);
  float acc[8] = {};
  for (int t = t0; t < t1; ++t) {
    const float w = expf(s[t] - m) * inv;
    const uint4 v = ((const uint4*)(hs_bf + (size_t)t * H_DIM))[tid];
    acc[0] += w * bf2f((unsigned short)(v.x & 0xffff));
    acc[1] += w * bf2f((unsigned short)(v.x >> 16));
    acc[2] += w * bf2f((unsigned short)(v.y & 0xffff));
    acc[3] += w * bf2f((unsigned short)(v.y >> 16));
    acc[4] += w * bf2f((unsigned short)(v.z & 0xffff));
    acc[5] += w * bf2f((unsigned short)(v.z >> 16));
    acc[6] += w * bf2f((unsigned short)(v.w & 0xffff));
    acc[7] += w * bf2f((unsigned short)(v.w >> 16));
  }
  float* dst = c_part + (size_t)blockIdx.x * H_DIM + tid * 8;
#pragma unroll
  for (int k = 0; k < 8; ++k) dst[k] = acc[k];
}

// ---------------- Phase 3d: reduce partials ----------------
__global__ __launch_bounds__(256) void reduce_c(
    const float* __restrict__ c_part, float* __restrict__ c) {
  const int i = blockIdx.x * 256 + threadIdx.x;
  float sum = 0.f;
  for (int b = 0; b < 64; ++b) sum += c_part[(size_t)b * H_DIM + i];
  c[i] = sum;
}

// ---------------- Phase 3e: output heads ----------------
__global__ __launch_bounds__(64) void logits_kernel(
    const float* __restrict__ W_o, const float* __restrict__ b_o,
    const float* __restrict__ W_d, const float* __restrict__ b_d,
    const float* __restrict__ c, float* __restrict__ out) {
  const int j = blockIdx.x;
  const int lane = threadIdx.x;
  const float* W; const float* bb; int jj;
  if (j < A_DIM) { W = W_o; bb = b_o; jj = j; }
  else { W = W_d; bb = b_d; jj = j - A_DIM; }
  const float4* w4 = (const float4*)(W + (size_t)jj * H_DIM);
  const float4* c4 = (const float4*)c;
  float sum = 0.f;
#pragma unroll
  for (int u = 0; u < 8; ++u) {
    float4 a = w4[lane + 64 * u];
    float4 b = c4[lane + 64 * u];
    sum += a.x * b.x + a.y * b.y + a.z * b.z + a.w * b.w;
  }
#pragma unroll
  for (int d = 32; d > 0; d >>= 1) sum += __shfl_xor(sum, d, 64);
  if (lane == 0) out[j] = sum + bb[jj];
}

extern "C" void kernel_launch(void* const* d_in, const int* in_sizes, int n_in,
                              void* d_out, int out_size, void* d_ws, size_t ws_size,
                              hipStream_t stream) {
  const float* obs  = (const float*)d_in[0];
  const float* W_ih = (const float*)d_in[1];
  const float* W_hh = (const float*)d_in[2];
  const float* b_ih = (const float*)d_in[3];
  const float* b_hh = (const float*)d_in[4];
  const float* W_o  = (const float*)d_in[5];
  const float* b_o  = (const float*)d_in[6];
  const float* W_d  = (const float*)d_in[7];
  const float* b_d  = (const float*)d_in[8];
  float* out = (float*)d_out;
  float* ws = (float*)d_ws;

  float* gxc      = ws + OFF_GXC;
  unsigned long long* htag = (unsigned long long*)(ws + OFF_HTAG);
  float* s        = ws + OFF_S;
  float* red      = ws + OFF_RED;
  float* c_part   = ws + OFF_CPART;
  float* c        = ws + OFF_C;
  unsigned short* hsbf16 = (unsigned short*)(ws + OFF_HSBF);

  // slot0 = {h=0, tag=0} for all units -> valid input for step t=0
  hipMemsetAsync(htag, 0, 2 * H_DIM * sizeof(unsigned long long), stream);

  for (int ci = 0; ci < T_DIM / CHUNK; ++ci) {
    gemm_gx<<<dim3(CHUNK / BM, G_DIM / BN), 256, 0, stream>>>(
        obs + (size_t)ci * CHUNK * O_DIM, W_ih, b_ih, gxc);
    scan_chunk<<<NBLK, 512, 0, stream>>>(
        W_hh, b_hh, gxc, htag, hsbf16, ci * CHUNK, CHUNK);
  }
  // final h (tag 8192, even) is in htag slot 0
  const unsigned long long* h_last = htag;

  const int n = T_DIM - 1;  // 8191 mid states
  attn_scores<<<(n + 3) / 4, 256, 0, stream>>>(hsbf16, h_last, s, n);
  softmax_stats<<<1, 1024, 0, stream>>>(s, n, red);
  attn_wsum<<<64, 256, 0, stream>>>(hsbf16, s, red, c_part, n);
  reduce_c<<<H_DIM / 256, 256, 0, stream>>>(c_part, c);
  logits_kernel<<<2 * A_DIM, 64, 0, stream>>>(W_o, b_o, W_d, b_d, c, out);
}

// Round 15
// 20324.306 us; speedup vs baseline: 1.2199x; 1.2199x over previous
//
#include <hip/hip_runtime.h>
#include <hip/hip_bf16.h>

#define T_DIM 8192
#define O_DIM 1024
#define H_DIM 2048
#define G_DIM 6144   // 3*H
#define A_DIM 512
#define CHUNK 512    // steps per scan launch
#define NBLK 256     // scan blocks (1 per CU; forced by dummy LDS)

// ---- workspace layout (float offsets; total ~46.7 MB, proven safe) ----
#define OFF_GXC   0ull          // CHUNK x 3H fp32            (3,145,728 f)
#define OFF_HTAG  3145728ull    // 2 x H u64 {h,tag}          (8,192 f)
#define OFF_S     3153920ull    // 8192 scores fp32
#define OFF_RED   3162112ull    // max, sum (+pad)            (16 f)
#define OFF_CPART 3162128ull    // 64 x 2048 fp32             (131,072 f)
#define OFF_C     3293200ull    // 2048 fp32
#define OFF_HSBF  3295248ull    // T x H bf16                 (8,388,608 f)

typedef __attribute__((ext_vector_type(8))) _Float16 half8;
typedef __attribute__((ext_vector_type(4))) float f32x4;

__device__ __forceinline__ float bf2f(unsigned short u) {
  return __uint_as_float(((unsigned)u) << 16);
}
__device__ __forceinline__ unsigned packbf(float a, float b) {
  return (unsigned)__bfloat16_as_ushort(__float2bfloat16(a)) |
         ((unsigned)__bfloat16_as_ushort(__float2bfloat16(b)) << 16);
}

// ---------------- Phase 1: gx chunk = obs_chunk @ W_ih^T + b_ih (MFMA fp16) ----
// 64x64 tile, BK=32, 4 waves; wave wv computes rows [wv*16,wv*16+16) x 64 cols
// as 4 mfma_f32_16x16x32_f16 accumulations. fp32->fp16 conversion on the fly
// during LDS staging (fp16 mantissa 2^-11: gx abs err ~5e-4, values << 65504).
// Layouts (m89-verified family): A/B frag row|col=lane&15, k=(lane>>4)*8+j;
// C/D col=lane&15, row=(lane>>4)*4+j. LDS rows padded to 40 halves (80B
// stride -> 2-way bank aliasing, free per m136).
__global__ __launch_bounds__(256) void gemm_gx_mfma(
    const float* __restrict__ A,   // CHUNK x O (obs chunk)
    const float* __restrict__ B,   // 3H x O (W_ih)
    const float* __restrict__ bias,
    float* __restrict__ C) {       // CHUNK x 3H
  __shared__ _Float16 As[64][40];
  __shared__ _Float16 Bs[64][40];
  const int tid = threadIdx.x;
  const int lane = tid & 63;
  const int wv = tid >> 6;
  const int bm = blockIdx.x * 64;
  const int bn = blockIdx.y * 64;
  const int srow = tid >> 2;          // staging row 0..63
  const int sseg = tid & 3;           // staging k-segment (8 floats)

  f32x4 acc0 = {0.f, 0.f, 0.f, 0.f};
  f32x4 acc1 = {0.f, 0.f, 0.f, 0.f};
  f32x4 acc2 = {0.f, 0.f, 0.f, 0.f};
  f32x4 acc3 = {0.f, 0.f, 0.f, 0.f};

  for (int k0 = 0; k0 < O_DIM; k0 += 32) {
    // ---- stage A,B slices (fp32 -> fp16), 8 floats per thread per matrix ----
    {
      const float4* ap = (const float4*)(A + (size_t)(bm + srow) * O_DIM + k0 + sseg * 8);
      const float4 a0 = ap[0], a1 = ap[1];
      half8 pa;
      pa[0] = (_Float16)a0.x; pa[1] = (_Float16)a0.y;
      pa[2] = (_Float16)a0.z; pa[3] = (_Float16)a0.w;
      pa[4] = (_Float16)a1.x; pa[5] = (_Float16)a1.y;
      pa[6] = (_Float16)a1.z; pa[7] = (_Float16)a1.w;
      *(half8*)&As[srow][sseg * 8] = pa;
      const float4* bp = (const float4*)(B + (size_t)(bn + srow) * O_DIM + k0 + sseg * 8);
      const float4 b0 = bp[0], b1 = bp[1];
      half8 pb;
      pb[0] = (_Float16)b0.x; pb[1] = (_Float16)b0.y;
      pb[2] = (_Float16)b0.z; pb[3] = (_Float16)b0.w;
      pb[4] = (_Float16)b1.x; pb[5] = (_Float16)b1.y;
      pb[6] = (_Float16)b1.z; pb[7] = (_Float16)b1.w;
      *(half8*)&Bs[srow][sseg * 8] = pb;
    }
    __syncthreads();

    // ---- fragments + 4 MFMA ----
    const half8 af = *(const half8*)&As[wv * 16 + (lane & 15)][(lane >> 4) * 8];
    const half8 bf0 = *(const half8*)&Bs[ 0 + (lane & 15)][(lane >> 4) * 8];
    const half8 bf1 = *(const half8*)&Bs[16 + (lane & 15)][(lane >> 4) * 8];
    const half8 bf2 = *(const half8*)&Bs[32 + (lane & 15)][(lane >> 4) * 8];
    const half8 bf3 = *(const half8*)&Bs[48 + (lane & 15)][(lane >> 4) * 8];
    acc0 = __builtin_amdgcn_mfma_f32_16x16x32_f16(af, bf0, acc0, 0, 0, 0);
    acc1 = __builtin_amdgcn_mfma_f32_16x16x32_f16(af, bf1, acc1, 0, 0, 0);
    acc2 = __builtin_amdgcn_mfma_f32_16x16x32_f16(af, bf2, acc2, 0, 0, 0);
    acc3 = __builtin_amdgcn_mfma_f32_16x16x32_f16(af, bf3, acc3, 0, 0, 0);
    __syncthreads();
  }

  // ---- epilogue: C/D col=lane&15, row=(lane>>4)*4+j ----
  const int coll = lane & 15;
  const int rowq = (lane >> 4) * 4;
#pragma unroll
  for (int j = 0; j < 4; ++j) {
    const int r = bm + wv * 16 + rowq + j;
    float* crow = C + (size_t)r * G_DIM + bn;
    crow[ 0 + coll] = acc0[j] + bias[bn +  0 + coll];
    crow[16 + coll] = acc1[j] + bias[bn + 16 + coll];
    crow[32 + coll] = acc2[j] + bias[bn + 32 + coll];
    crow[48 + coll] = acc3[j] + bias[bn + 48 + coll];
  }
}

// unpack-and-FMA one packed-bf16 uint4 (8 cols) against two staged float4s
#define DOTQ(Q, ACC)                                                  \
  do {                                                                \
    ACC += __uint_as_float((Q).x << 16)          * ha.x               \
         + __uint_as_float((Q).x & 0xffff0000u)  * ha.y               \
         + __uint_as_float((Q).y << 16)          * ha.z               \
         + __uint_as_float((Q).y & 0xffff0000u)  * ha.w               \
         + __uint_as_float((Q).z << 16)          * hb.x               \
         + __uint_as_float((Q).z & 0xffff0000u)  * hb.y               \
         + __uint_as_float((Q).w << 16)          * hb.z               \
         + __uint_as_float((Q).w & 0xffff0000u)  * hb.w;              \
  } while (0)

// ---------------- Phase 2: persistent GRU scan (r12 champion, verbatim) -------
__global__ __launch_bounds__(512, 2) void scan_chunk(
    const float* __restrict__ W_hh,        // 3H x H fp32
    const float* __restrict__ b_hh,        // 3H
    const float* __restrict__ gxc,         // CHUNK x 3H
    unsigned long long* __restrict__ htag, // 2 x H {h,tag}
    unsigned short* __restrict__ hsbf16,   // T x H bf16
    int t0, int nsteps) {
  __shared__ char smem[98304];             // forces 1 block/CU
  float* hlbuf0 = (float*)smem;                          // H_DIM floats
  float* hlbuf1 = (float*)(smem + 8192);                 // H_DIM floats
  unsigned long long* stage = (unsigned long long*)(smem + 16384);  // 8 u64
  const int tid = threadIdx.x;
  const int lane = tid & 63;
  const int wv = tid >> 6;                 // wave 0..7
  const int blk = blockIdx.x;
  const int u = blk * 8 + wv;              // owned unit

  // ---- weights: fp32 load -> packed bf16 in 12 named uint4 ----
  const float4* wr0 = (const float4*)(W_hh + (size_t)(0 * H_DIM + u) * H_DIM);
  const float4* wr1 = (const float4*)(W_hh + (size_t)(1 * H_DIM + u) * H_DIM);
  const float4* wr2 = (const float4*)(W_hh + (size_t)(2 * H_DIM + u) * H_DIM);
#define LOADQ(WR, J2)                                                  \
  ({ const float4 lo = (WR)[lane + 128 * (J2)];                        \
     const float4 hi = (WR)[lane + 64 + 128 * (J2)];                   \
     uint4{packbf(lo.x, lo.y), packbf(lo.z, lo.w),                     \
           packbf(hi.x, hi.y), packbf(hi.z, hi.w)}; })
  const uint4 q00 = LOADQ(wr0, 0), q01 = LOADQ(wr0, 1),
              q02 = LOADQ(wr0, 2), q03 = LOADQ(wr0, 3);
  const uint4 q10 = LOADQ(wr1, 0), q11 = LOADQ(wr1, 1),
              q12 = LOADQ(wr1, 2), q13 = LOADQ(wr1, 3);
  const uint4 q20 = LOADQ(wr2, 0), q21 = LOADQ(wr2, 1),
              q22 = LOADQ(wr2, 2), q23 = LOADQ(wr2, 3);
#undef LOADQ

  float b0 = 0.f, b1 = 0.f, b2 = 0.f;
  if (lane == 0) {
    b0 = b_hh[u]; b1 = b_hh[H_DIM + u]; b2 = b_hh[2 * H_DIM + u];
  }

  for (int tt = 0; tt < nsteps; ++tt) {
    const int t = t0 + tt;
    const unsigned long long* hin = htag + (size_t)(t & 1) * H_DIM;
    unsigned long long* hout = htag + (size_t)((t + 1) & 1) * H_DIM;
    float* hl = (t & 1) ? hlbuf1 : hlbuf0;   // double-buffered stage

    // gx for owner lane (issued early; drains at the barrier after poll)
    float gx0 = 0.f, gx1 = 0.f, gx2 = 0.f;
    if (lane == 0) {
      const float* g = gxc + (size_t)tt * G_DIM + u;
      gx0 = g[0]; gx1 = g[H_DIM]; gx2 = g[2 * H_DIM];
    }

    // ---- (A) poll-the-data: 4 u64/thread, coalesced; tag+h in one word ----
    unsigned long long v[4];
    const unsigned tgt = (unsigned)t;
    for (;;) {
      bool ok = true;
#pragma unroll
      for (int j = 0; j < 4; ++j) {
        v[j] = __hip_atomic_load(hin + tid + 512 * j,
                                 __ATOMIC_RELAXED, __HIP_MEMORY_SCOPE_AGENT);
        ok = ok && ((unsigned)v[j] >= tgt);
      }
      if (ok) break;
      __builtin_amdgcn_s_sleep(1);
    }
#pragma unroll
    for (int j = 0; j < 4; ++j)
      hl[tid + 512 * j] = __uint_as_float((unsigned)(v[j] >> 32));
    __syncthreads();   // (B) hl ready

    // ---- (C) 3 dot products off packed-bf16 register weights ----
    float a0 = 0.f, a1 = 0.f, a2 = 0.f;
    const float4* h4 = (const float4*)hl;
    {
      float4 ha, hb;
      ha = h4[lane +   0]; hb = h4[lane +  64];
      DOTQ(q00, a0); DOTQ(q10, a1); DOTQ(q20, a2);
      ha = h4[lane + 128]; hb = h4[lane + 192];
      DOTQ(q01, a0); DOTQ(q11, a1); DOTQ(q21, a2);
      ha = h4[lane + 256]; hb = h4[lane + 320];
      DOTQ(q02, a0); DOTQ(q12, a1); DOTQ(q22, a2);
      ha = h4[lane + 384]; hb = h4[lane + 448];
      DOTQ(q03, a0); DOTQ(q13, a1); DOTQ(q23, a2);
    }
#pragma unroll
    for (int d = 32; d > 0; d >>= 1) {
      a0 += __shfl_xor(a0, d, 64);
      a1 += __shfl_xor(a1, d, 64);
      a2 += __shfl_xor(a2, d, 64);
    }

    // ---- (D) gates on owner lane; stage {h,tag} in LDS ----
    float hnew = 0.f;
    if (lane == 0) {
      const float rr = 1.f / (1.f + expf(-(gx0 + a0 + b0)));
      const float zz = 1.f / (1.f + expf(-(gx1 + a1 + b1)));
      const float nn = tanhf(gx2 + rr * (a2 + b2));
      hnew = (1.f - zz) * nn + zz * hl[u];
      stage[wv] = ((unsigned long long)__float_as_uint(hnew) << 32) |
                  (unsigned long long)(unsigned)(t + 1);
    }
    __syncthreads();   // (E) stage ready

    // ---- (F) single-wave coalesced publish: one 64B line, one instruction ----
    if (tid < 8) {
      __hip_atomic_store(hout + blk * 8 + tid, stage[tid],
                         __ATOMIC_RELAXED, __HIP_MEMORY_SCOPE_AGENT);
    }
    // ---- (G) attention state (off critical path; drains under next poll) ----
    if (lane == 0) {
      hsbf16[(size_t)t * H_DIM + u] =
          (unsigned short)__bfloat16_as_ushort(__float2bfloat16(hnew));
    }
  }
}

// ---------------- Phase 3a: attention scores (bf16 h_mid, h_last from htag) ---
__global__ __launch_bounds__(256) void attn_scores(
    const unsigned short* __restrict__ hs_bf,
    const unsigned long long* __restrict__ hq,  // slot0 of htag: {h,tag=8192}
    float* __restrict__ s, int n) {
  __shared__ float hl[H_DIM];
  const int tid = threadIdx.x;
  for (int i = tid; i < H_DIM; i += 256)
    hl[i] = __uint_as_float((unsigned)(hq[i] >> 32));
  __syncthreads();
  const int wave = tid >> 6, lane = tid & 63;
  const int t = blockIdx.x * 4 + wave;
  if (t >= n) return;
  const uint4* r4 = (const uint4*)(hs_bf + (size_t)t * H_DIM);
  float sum = 0.f;
#pragma unroll
  for (int u = 0; u < 4; ++u) {
    const int idx = lane + 64 * u;
    uint4 v = r4[idx];
    const float* l = hl + idx * 8;
    sum += bf2f((unsigned short)(v.x & 0xffff)) * l[0];
    sum += bf2f((unsigned short)(v.x >> 16))    * l[1];
    sum += bf2f((unsigned short)(v.y & 0xffff)) * l[2];
    sum += bf2f((unsigned short)(v.y >> 16))    * l[3];
    sum += bf2f((unsigned short)(v.z & 0xffff)) * l[4];
    sum += bf2f((unsigned short)(v.z >> 16))    * l[5];
    sum += bf2f((unsigned short)(v.w & 0xffff)) * l[6];
    sum += bf2f((unsigned short)(v.w >> 16))    * l[7];
  }
#pragma unroll
  for (int d = 32; d > 0; d >>= 1) sum += __shfl_xor(sum, d, 64);
  if (lane == 0) s[t] = sum;
}

// ---------------- Phase 3b: softmax stats ----------------
__global__ __launch_bounds__(1024) void softmax_stats(
    const float* __restrict__ s, int n, float* __restrict__ red) {
  __shared__ float buf[1024];
  const int tid = threadIdx.x;
  float m = -3.4e38f;
  for (int i = tid; i < n; i += 1024) m = fmaxf(m, s[i]);
  buf[tid] = m;
  __syncthreads();
  for (int d = 512; d > 0; d >>= 1) {
    if (tid < d) buf[tid] = fmaxf(buf[tid], buf[tid + d]);
    __syncthreads();
  }
  const float mm = buf[0];
  __syncthreads();
  float sum = 0.f;
  for (int i = tid; i < n; i += 1024) sum += expf(s[i] - mm);
  buf[tid] = sum;
  __syncthreads();
  for (int d = 512; d > 0; d >>= 1) {
    if (tid < d) buf[tid] += buf[tid + d];
    __syncthreads();
  }
  if (tid == 0) { red[0] = mm; red[1] = buf[0]; }
}

// ---------------- Phase 3c: weighted sum partials (bf16 h_mid) ----------------
__global__ __launch_bounds__(256) void attn_wsum(
    const unsigned short* __restrict__ hs_bf, const float* __restrict__ s,
    const float* __restrict__ red, float* __restrict__ c_part, int n) {
  const int tid = threadIdx.x;
  const float m = red[0];
  const float inv = 1.f / red[1];
  const int tchunk = (n + 63) / 64;
  const int t0 = blockIdx.x * tchunk;
  const int t1 = min(t0 + tchunk, n);
  float acc[8] = {};
  for (int t = t0; t < t1; ++t) {
    const float w = expf(s[t] - m) * inv;
    const uint4 v = ((const uint4*)(hs_bf + (size_t)t * H_DIM))[tid];
    acc[0] += w * bf2f((unsigned short)(v.x & 0xffff));
    acc[1] += w * bf2f((unsigned short)(v.x >> 16));
    acc[2] += w * bf2f((unsigned short)(v.y & 0xffff));
    acc[3] += w * bf2f((unsigned short)(v.y >> 16));
    acc[4] += w * bf2f((unsigned short)(v.z & 0xffff));
    acc[5] += w * bf2f((unsigned short)(v.z >> 16));
    acc[6] += w * bf2f((unsigned short)(v.w & 0xffff));
    acc[7] += w * bf2f((unsigned short)(v.w >> 16));
  }
  float* dst = c_part + (size_t)blockIdx.x * H_DIM + tid * 8;
#pragma unroll
  for (int k = 0; k < 8; ++k) dst[k] = acc[k];
}

// ---------------- Phase 3d: reduce partials ----------------
__global__ __launch_bounds__(256) void reduce_c(
    const float* __restrict__ c_part, float* __restrict__ c) {
  const int i = blockIdx.x * 256 + threadIdx.x;
  float sum = 0.f;
  for (int b = 0; b < 64; ++b) sum += c_part[(size_t)b * H_DIM + i];
  c[i] = sum;
}

// ---------------- Phase 3e: output heads ----------------
__global__ __launch_bounds__(64) void logits_kernel(
    const float* __restrict__ W_o, const float* __restrict__ b_o,
    const float* __restrict__ W_d, const float* __restrict__ b_d,
    const float* __restrict__ c, float* __restrict__ out) {
  const int j = blockIdx.x;
  const int lane = threadIdx.x;
  const float* W; const float* bb; int jj;
  if (j < A_DIM) { W = W_o; bb = b_o; jj = j; }
  else { W = W_d; bb = b_d; jj = j - A_DIM; }
  const float4* w4 = (const float4*)(W + (size_t)jj * H_DIM);
  const float4* c4 = (const float4*)c;
  float sum = 0.f;
#pragma unroll
  for (int u = 0; u < 8; ++u) {
    float4 a = w4[lane + 64 * u];
    float4 b = c4[lane + 64 * u];
    sum += a.x * b.x + a.y * b.y + a.z * b.z + a.w * b.w;
  }
#pragma unroll
  for (int d = 32; d > 0; d >>= 1) sum += __shfl_xor(sum, d, 64);
  if (lane == 0) out[j] = sum + bb[jj];
}

extern "C" void kernel_launch(void* const* d_in, const int* in_sizes, int n_in,
                              void* d_out, int out_size, void* d_ws, size_t ws_size,
                              hipStream_t stream) {
  const float* obs  = (const float*)d_in[0];
  const float* W_ih = (const float*)d_in[1];
  const float* W_hh = (const float*)d_in[2];
  const float* b_ih = (const float*)d_in[3];
  const float* b_hh = (const float*)d_in[4];
  const float* W_o  = (const float*)d_in[5];
  const float* b_o  = (const float*)d_in[6];
  const float* W_d  = (const float*)d_in[7];
  const float* b_d  = (const float*)d_in[8];
  float* out = (float*)d_out;
  float* ws = (float*)d_ws;

  float* gxc      = ws + OFF_GXC;
  unsigned long long* htag = (unsigned long long*)(ws + OFF_HTAG);
  float* s        = ws + OFF_S;
  float* red      = ws + OFF_RED;
  float* c_part   = ws + OFF_CPART;
  float* c        = ws + OFF_C;
  unsigned short* hsbf16 = (unsigned short*)(ws + OFF_HSBF);

  // slot0 = {h=0, tag=0} for all units -> valid input for step t=0
  hipMemsetAsync(htag, 0, 2 * H_DIM * sizeof(unsigned long long), stream);

  for (int ci = 0; ci < T_DIM / CHUNK; ++ci) {
    gemm_gx_mfma<<<dim3(CHUNK / 64, G_DIM / 64), 256, 0, stream>>>(
        obs + (size_t)ci * CHUNK * O_DIM, W_ih, b_ih, gxc);
    scan_chunk<<<NBLK, 512, 0, stream>>>(
        W_hh, b_hh, gxc, htag, hsbf16, ci * CHUNK, CHUNK);
  }
  // final h (tag 8192, even) is in htag slot 0
  const unsigned long long* h_last = htag;

  const int n = T_DIM - 1;  // 8191 mid states
  attn_scores<<<(n + 3) / 4, 256, 0, stream>>>(hsbf16, h_last, s, n);
  softmax_stats<<<1, 1024, 0, stream>>>(s, n, red);
  attn_wsum<<<64, 256, 0, stream>>>(hsbf16, s, red, c_part, n);
  reduce_c<<<H_DIM / 256, 256, 0, stream>>>(c_part, c);
  logits_kernel<<<2 * A_DIM, 64, 0, stream>>>(W_o, b_o, W_d, b_d, c, out);
}